// Round 9
// baseline (1374.436 us; speedup 1.0000x reference)
//
#include <hip/hip_runtime.h>
#include <math.h>

#define B    32
#define INF  784
#define H1   1024
#define H2   1024
#define NC   10
#define EPSV 0.1f
#define NBLK 768

typedef __attribute__((ext_vector_type(8))) short short8;
typedef __attribute__((ext_vector_type(4))) float floatx4;

__device__ inline ushort bf16_rne(float f) {
  uint u = __builtin_bit_cast(uint, f);
  u += 0x7FFFu + ((u >> 16) & 1u);
  return (ushort)(u >> 16);
}
__device__ inline uint pack2(float a, float b) {
  return (uint)bf16_rne(a) | ((uint)bf16_rne(b) << 16);
}
__device__ inline uint scale_pack(uint u, float d0, float d1v) {
  float f0 = __builtin_bit_cast(float, u << 16) * d0;
  float f1 = __builtin_bit_cast(float, u & 0xFFFF0000u) * d1v;
  uint r0 = __builtin_bit_cast(uint, f0) + 0x8000u;
  uint r1 = __builtin_bit_cast(uint, f1) + 0x8000u;
  return __builtin_amdgcn_perm(r1, r0, 0x07060302u);
}

// Device-scope generation barrier.  All NBLK blocks are co-resident by
// construction (launch_bounds(256,3): <=170 VGPR, 9.2 KB LDS -> 3 blocks/CU).
__device__ inline void grid_sync(uint* bar, uint nblocks) {
  __syncthreads();
  if (threadIdx.x == 0) {
    __threadfence();
    uint g = __hip_atomic_load(bar + 1, __ATOMIC_RELAXED, __HIP_MEMORY_SCOPE_AGENT);
    uint prev = __hip_atomic_fetch_add(bar, 1u, __ATOMIC_ACQ_REL, __HIP_MEMORY_SCOPE_AGENT);
    if (prev == nblocks - 1u) {
      __hip_atomic_store(bar, 0u, __ATOMIC_RELAXED, __HIP_MEMORY_SCOPE_AGENT);
      __hip_atomic_store(bar + 1, g + 1u, __ATOMIC_RELEASE, __HIP_MEMORY_SCOPE_AGENT);
    } else {
      while (__hip_atomic_load(bar + 1, __ATOMIC_ACQUIRE, __HIP_MEMORY_SCOPE_AGENT) == g) {
        __builtin_amdgcn_s_sleep(1);
      }
    }
    __threadfence();
  }
  __syncthreads();
}

#define K3_LOAD(c, A, Bv) do {                                                  \
  _Pragma("unroll")                                                             \
  for (int ni = 0; ni < 2; ni++)                                                \
    Bv[ni] = *reinterpret_cast<const uint4*>(bBase + (size_t)(c) * 32768 + ni * 512); \
  _Pragma("unroll")                                                             \
  for (int mi = 0; mi < 7; mi++)                                                \
    A[mi] = *reinterpret_cast<const uint4*>(aBase + (size_t)(c) * 25088 + mi * 512); \
} while (0)

#define K3F_COMP(c, A, Bv) do {                                                 \
  float4 dv0 = *reinterpret_cast<const float4*>(&sm.Ds[(c) * 32 + quad * 8]);   \
  float4 dv1 = *reinterpret_cast<const float4*>(&sm.Ds[(c) * 32 + quad * 8 + 4]);\
  short8 bfr[2];                                                                \
  _Pragma("unroll")                                                             \
  for (int ni = 0; ni < 2; ni++) {                                              \
    uint4 sb;                                                                   \
    sb.x = scale_pack(Bv[ni].x, dv0.x, dv0.y);                                  \
    sb.y = scale_pack(Bv[ni].y, dv0.z, dv0.w);                                  \
    sb.z = scale_pack(Bv[ni].z, dv1.x, dv1.y);                                  \
    sb.w = scale_pack(Bv[ni].w, dv1.z, dv1.w);                                  \
    bfr[ni] = __builtin_bit_cast(short8, sb);                                   \
  }                                                                             \
  _Pragma("unroll")                                                             \
  for (int mi = 0; mi < 7; mi++) {                                              \
    short8 af = __builtin_bit_cast(short8, A[mi]);                              \
    _Pragma("unroll")                                                           \
    for (int ni = 0; ni < 2; ni++)                                              \
      acc[mi][ni] = __builtin_amdgcn_mfma_f32_16x16x32_bf16(af, bfr[ni], acc[mi][ni], 0, 0, 0); \
  }                                                                             \
} while (0)

__global__ __launch_bounds__(256, 3) void k_mega(
    const float* __restrict__ x, const int* __restrict__ y,
    const float* __restrict__ W1, const float* __restrict__ b1,
    const float* __restrict__ W2, const float* __restrict__ b2,
    const float* __restrict__ W3, const float* __restrict__ b3,
    float* __restrict__ out, float* __restrict__ ws)
{
  float* d1B   = ws;
  float* t1B   = ws + 32768;
  float* dnB   = ws + 65536;
  float* E     = ws + 196608;   // 32768, zeroed in P0
  float* F     = ws + 229376;   // 1024, zeroed in P0
  float* F2    = ws + 230400;   // 20480, zeroed in P0
  float* nu2T  = ws + 328704;   // 393216
  ushort* W2F  = (ushort*)(ws + 721920);
  ushort* W1F  = (ushort*)(ws + 1246208);
  float* nu1fT = ws + 328704;   // overlay (after nu2T dead)
  float* hpart = ws + 721920;   // overlay (after W2F/W1F dead)
  float* ppart = ws + 721920;   // overlay (after hpart dead)
  uint* bar    = (uint*)(ws + 4000000);  // zeroed by hipMemsetAsync

  int bid = blockIdx.x;
  int t = threadIdx.x;
  int w = t >> 6, lane = t & 63;
  int quad = lane >> 4, l15 = lane & 15;

  __shared__ union {
    struct { float red[4][B + 1]; float Ts[4][32][17]; } p0;
    float Ds[H1];
    struct { float sA[B], sCl[B], sCu[B], sd2[B], st2[B], sdb[B], swy[B], sw3[NC]; } p2;
    struct { float red[4][2 * NC]; } p4;
    struct { float red[4][NC]; } p6;
  } sm;

  // ================= P0: pack + layer-1 + zero-init (1487 virtual) ========
  for (int vb = bid; vb < 1487; vb += NBLK) {
    __syncthreads();
    if (vb < 64) {
      int jt = vb;
      for (int c = w; c < 32; c += 4) {
        const float* src = &W2[(size_t)(jt * 16 + l15) * H1 + c * 32 + quad * 8];
        float4 v0 = *reinterpret_cast<const float4*>(src);
        float4 v1 = *reinterpret_cast<const float4*>(src + 4);
        uint4 o;
        o.x = pack2(v0.x, v0.y); o.y = pack2(v0.z, v0.w);
        o.z = pack2(v1.x, v1.y); o.w = pack2(v1.z, v1.w);
        *reinterpret_cast<uint4*>(&W2F[((size_t)(c * 64 + jt) * 64 + lane) * 8]) = o;
      }
    } else if (vb < 456) {
      int idx = vb - 64;
      int mt = idx >> 3, cg = idx & 7;
      int c = cg * 4 + w;
      int col0 = mt * 16;
#pragma unroll
      for (int p = 0; p < 8; p++) {
        int r = p * 4 + (lane >> 4);
        sm.p0.Ts[w][r][lane & 15] = W1[(size_t)(c * 32 + r) * INF + col0 + (lane & 15)];
      }
      float f[8];
#pragma unroll
      for (int e = 0; e < 8; e++) f[e] = sm.p0.Ts[w][quad * 8 + e][l15];
      uint4 o;
      o.x = pack2(f[0], f[1]); o.y = pack2(f[2], f[3]);
      o.z = pack2(f[4], f[5]); o.w = pack2(f[6], f[7]);
      *reinterpret_cast<uint4*>(&W1F[((size_t)(c * 49 + mt) * 64 + lane) * 8]) = o;
    } else if (vb < 1480) {
      int i = vb - 456;
      const float* wr = W1 + (size_t)i * INF;
      float acc[B];
#pragma unroll
      for (int b = 0; b < B; b++) acc[b] = 0.f;
      float wabs = 0.f;
      for (int k = t; k < INF; k += 256) {
        float wv = wr[k];
        wabs += fabsf(wv);
#pragma unroll
        for (int b = 0; b < B; b++) acc[b] = fmaf(x[b * INF + k], wv, acc[b]);
      }
#pragma unroll
      for (int off = 32; off > 0; off >>= 1) {
#pragma unroll
        for (int b = 0; b < B; b++) acc[b] += __shfl_down(acc[b], off, 64);
        wabs += __shfl_down(wabs, off, 64);
      }
      if (lane == 0) {
#pragma unroll
        for (int b = 0; b < B; b++) sm.p0.red[w][b] = acc[b];
        sm.p0.red[w][B] = wabs;
      }
      __syncthreads();
      if (t < B) {
        float s = sm.p0.red[0][t] + sm.p0.red[1][t] + sm.p0.red[2][t] + sm.p0.red[3][t];
        float r = EPSV * (sm.p0.red[0][B] + sm.p0.red[1][B] + sm.p0.red[2][B] + sm.p0.red[3][B]);
        float nom = s + b1[i];
        float zl = nom - r, zu = nom + r;
        float d, l;
        if (zl >= 0.f)      { d = 1.f;            l = 0.f; }
        else if (zu > 0.f)  { d = zu / (zu - zl); l = zl;  }
        else                { d = 0.f;            l = 0.f; }
        d1B[(size_t)t * H1 + i] = d;
        t1B[(size_t)t * H1 + i] = d * l;
        dnB[(size_t)t * H1 + i] = d * nom;
      }
    } else {
      int zb = vb - 1480;
      for (int idx = t; idx < 8192; idx += 256) {
        int pos = zb * 8192 + idx;
        if (pos < 54272) E[pos] = 0.f;   // covers E, F, F2 (contiguous)
      }
    }
  }
  grid_sync(bar, NBLK);

  // ================= P1: E-GEMM (1792 virtual: x7, y8, b32) ===============
  for (int vb = bid; vb < 1792; vb += NBLK) {
    __syncthreads();
    int xg = vb % 7;
    int rem = vb / 7;
    int yg = rem & 7;
    int b = rem >> 3;
    int mt0 = xg * 7;
    int jt0 = yg * 8 + w * 2;

    for (int idx = t; idx < H1; idx += 256) sm.Ds[idx] = d1B[(size_t)b * H1 + idx];
    __syncthreads();

    const ushort* aBase = W1F + ((size_t)mt0 * 64 + lane) * 8;
    const ushort* bBase = W2F + ((size_t)jt0 * 64 + lane) * 8;

    floatx4 acc[7][2];
#pragma unroll
    for (int mi = 0; mi < 7; mi++)
#pragma unroll
      for (int ni = 0; ni < 2; ni++) acc[mi][ni] = (floatx4){0.f, 0.f, 0.f, 0.f};

    uint4 a0[7], b0[2], a1[7], b1v[2];
    K3_LOAD(0, a0, b0);
    K3_LOAD(1, a1, b1v);
    for (int c = 0; c < 30; c += 2) {
      K3F_COMP(c, a0, b0);
      K3_LOAD(c + 2, a0, b0);
      K3F_COMP(c + 1, a1, b1v);
      if (c + 3 < 32) K3_LOAD(c + 3, a1, b1v);
    }
    K3F_COMP(30, a0, b0);
    K3F_COMP(31, a1, b1v);

#pragma unroll
    for (int ni = 0; ni < 2; ni++) {
      float s = 0.f;
#pragma unroll
      for (int mi = 0; mi < 7; mi++)
#pragma unroll
        for (int r = 0; r < 4; r++) s += fabsf(acc[mi][ni][r]);
      s += __shfl_xor(s, 16, 64);
      s += __shfl_xor(s, 32, 64);
      if (lane < 16) {
        int j = (jt0 + ni) * 16 + l15;
        atomicAdd(&E[(size_t)j * B + b], EPSV * s);
      }
    }
  }
  grid_sync(bar, NBLK);

  // ================= P2: k2+k4+k5a fused (1024 virtual, j = vb) ===========
  for (int vb = bid; vb < 1024; vb += NBLK) {
    __syncthreads();
    int j = vb;
    int b0 = w * 8;
    float aA[8] = {}, aCl[8] = {}, aCu[8] = {};
    const float* __restrict__ w2 = W2 + (size_t)j * H1;
    for (int i = lane; i < H1; i += 64) {
      float wv = w2[i];
      float wp = fmaxf(wv, 0.f), wn = fmaxf(-wv, 0.f);
#pragma unroll
      for (int r = 0; r < 8; r++) {
        float dv = dnB[(size_t)(b0 + r) * H1 + i];
        float tv = t1B[(size_t)(b0 + r) * H1 + i];
        aA[r]  = fmaf(wv, dv, aA[r]);
        aCl[r] = fmaf(wn, tv, aCl[r]);
        aCu[r] = fmaf(wp, tv, aCu[r]);
      }
    }
#pragma unroll
    for (int off = 32; off > 0; off >>= 1) {
#pragma unroll
      for (int r = 0; r < 8; r++) {
        aA[r]  += __shfl_down(aA[r],  off, 64);
        aCl[r] += __shfl_down(aCl[r], off, 64);
        aCu[r] += __shfl_down(aCu[r], off, 64);
      }
    }
    float bj = b2[j];
    if (lane == 0) {
#pragma unroll
      for (int r = 0; r < 8; r++) {
        sm.p2.sA [b0 + r] = aA[r] + bj;
        sm.p2.sCl[b0 + r] = aCl[r];
        sm.p2.sCu[b0 + r] = aCu[r];
      }
    }
    if (t >= 64 && t < 96)   sm.p2.swy[t - 64]  = W3[(size_t)y[t - 64] * H2 + j];
    if (t >= 128 && t < 138) sm.p2.sw3[t - 128] = W3[(size_t)(t - 128) * H2 + j];
    __syncthreads();
    if (t < B) {
      float a = sm.p2.sA[t], e = E[(size_t)j * B + t];
      float zl = a - e + sm.p2.sCl[t];
      float zu = a + e - sm.p2.sCu[t];
      float d, l;
      if (zl >= 0.f)      { d = 1.f;            l = 0.f; }
      else if (zu > 0.f)  { d = zu / (zu - zl); l = zl;  }
      else                { d = 0.f;            l = 0.f; }
      sm.p2.sd2[t] = d;
      sm.p2.st2[t] = d * l;
      sm.p2.sdb[t] = d * bj;
    }
    __syncthreads();
    for (int tt = t; tt < B * NC; tt += 256) {   // B*NC=320 > 256: strided
      int b = tt / NC, jc = tt - b * NC;
      float cw = sm.p2.swy[b] - sm.p2.sw3[jc];
      float d2v = sm.p2.sd2[b];
      nu2T[((size_t)b * H2 + j) * 12 + jc] = cw * d2v;
      float val = cw * sm.p2.sdb[b] + fmaxf(-cw, 0.f) * sm.p2.st2[b];
      atomicAdd(&F2[((size_t)(j & 63) * B + b) * NC + jc], val);
    }
  }
  grid_sync(bar, NBLK);

  // ================= P3: k5b1 (512 virtual: x2, b32, s8) ==================
  for (int vb = bid; vb < 512; vb += NBLK) {
    int xg = vb & 1, b = (vb >> 1) & 31, s = vb >> 6;
    int i1 = xg * 512 + t * 2;
    const float* __restrict__ nrowb = nu2T + ((size_t)b * H2 + s * 128) * 12;
    const float* __restrict__ w2b = W2 + (size_t)s * 128 * H1 + i1;
    float h0[NC] = {}, h1[NC] = {};
    for (int i2 = 0; i2 < 128; i2++) {
      float2 wv = *reinterpret_cast<const float2*>(&w2b[(size_t)i2 * H1]);
      const float* __restrict__ nrow = nrowb + i2 * 12;
#pragma unroll
      for (int j = 0; j < NC; j++) {
        h0[j] = fmaf(nrow[j], wv.x, h0[j]);
        h1[j] = fmaf(nrow[j], wv.y, h1[j]);
      }
    }
#pragma unroll
    for (int j = 0; j < NC; j++) {
      float2 o; o.x = h0[j]; o.y = h1[j];
      *reinterpret_cast<float2*>(&hpart[(((size_t)s * B + b) * NC + j) * H1 + i1]) = o;
    }
  }
  grid_sync(bar, NBLK);

  // ================= P4: k5b2 (128 virtual: x4, b32) ======================
  for (int vb = bid; vb < 128; vb += NBLK) {
    __syncthreads();
    int xg = vb & 3, b = vb >> 2;
    int i1 = xg * 256 + t;
    float d1v = d1B[(size_t)b * H1 + i1];
    float t1v = t1B[(size_t)b * H1 + i1];
    float dnv = dnB[(size_t)b * H1 + i1];
    float sn[NC], c1[NC];
#pragma unroll
    for (int j = 0; j < NC; j++) {
      float hv = 0.f;
#pragma unroll
      for (int s = 0; s < 8; s++)
        hv += hpart[(((size_t)s * B + b) * NC + j) * H1 + i1];
      nu1fT[((size_t)b * H1 + i1) * 12 + j] = hv * d1v;
      sn[j] = hv * dnv;
      c1[j] = fmaxf(-hv, 0.f) * t1v;
    }
#pragma unroll
    for (int off = 32; off > 0; off >>= 1) {
#pragma unroll
      for (int j = 0; j < NC; j++) {
        sn[j] += __shfl_down(sn[j], off, 64);
        c1[j] += __shfl_down(c1[j], off, 64);
      }
    }
    if (lane == 0) {
#pragma unroll
      for (int j = 0; j < NC; j++) { sm.p4.red[w][j] = sn[j]; sm.p4.red[w][NC + j] = c1[j]; }
    }
    __syncthreads();
    if (t < NC) {
      float s = 0.f;
      for (int ww = 0; ww < 4; ww++) s += sm.p4.red[ww][t] + sm.p4.red[ww][NC + t];
      atomicAdd(&F[b * NC + t], s);
    }
  }
  grid_sync(bar, NBLK);

  // ================= P5: k5c1 (1024 virtual: kk4, b32, s8; 196 active) ====
  for (int vb = bid; vb < 1024; vb += NBLK) {
    int kk = vb & 3, b = (vb >> 2) & 31, s = vb >> 7;
    bool valid = (t < 196);
    int k = kk * 196 + (valid ? t : 0);
    const float* __restrict__ nrowb = nu1fT + ((size_t)b * H1 + s * 128) * 12;
    const float* __restrict__ w1b = W1 + (size_t)s * 128 * INF + k;
    float acc[NC] = {};
    for (int i1 = 0; i1 < 128; i1++) {
      float w1v = w1b[(size_t)i1 * INF];
      const float* __restrict__ nrow = nrowb + i1 * 12;
#pragma unroll
      for (int j = 0; j < NC; j++) acc[j] = fmaf(nrow[j], w1v, acc[j]);
    }
    if (valid) {
#pragma unroll
      for (int j = 0; j < NC; j++)
        ppart[(((size_t)s * B + b) * NC + j) * INF + k] = acc[j];
    }
  }
  grid_sync(bar, NBLK);

  // ================= P6: k5c2 + out (32 virtual) ==========================
  for (int vb = bid; vb < 32; vb += NBLK) {
    __syncthreads();
    int b = vb;
    float e[NC] = {};
    for (int k = t; k < INF; k += 256) {
#pragma unroll
      for (int j = 0; j < NC; j++) {
        float v = 0.f;
#pragma unroll
        for (int s = 0; s < 8; s++)
          v += ppart[(((size_t)s * B + b) * NC + j) * INF + k];
        e[j] += fabsf(v);
      }
    }
#pragma unroll
    for (int off = 32; off > 0; off >>= 1) {
#pragma unroll
      for (int j = 0; j < NC; j++) e[j] += __shfl_down(e[j], off, 64);
    }
    if (lane == 0) {
#pragma unroll
      for (int j = 0; j < NC; j++) sm.p6.red[w][j] = e[j];
    }
    __syncthreads();
    if (t < NC) {
      float ef = 0.f;
      for (int ww = 0; ww < 4; ww++) ef += sm.p6.red[ww][t];
      float s = F[b * NC + t];
      for (int slot = 0; slot < 64; slot++)
        s += F2[((size_t)slot * B + b) * NC + t];
      int yb = y[b];
      s += b3[yb] - b3[t];
      out[b * NC + t] = EPSV * ef - s;
    }
  }
}

// ---------------------------------------------------------------------------
extern "C" void kernel_launch(void* const* d_in, const int* in_sizes, int n_in,
                              void* d_out, int out_size, void* d_ws, size_t ws_size,
                              hipStream_t stream) {
  const float* x  = (const float*)d_in[0];
  const int*   y  = (const int*)  d_in[1];
  const float* W1 = (const float*)d_in[2];
  const float* b1 = (const float*)d_in[3];
  const float* W2 = (const float*)d_in[4];
  const float* b2 = (const float*)d_in[5];
  const float* W3 = (const float*)d_in[6];
  const float* b3 = (const float*)d_in[7];
  float* out = (float*)d_out;
  float* ws  = (float*)d_ws;

  // barrier vars (2 uints) at float-offset 4,000,000 (16 MB) — beyond all
  // overlays (max overlay end = 3,343,360 floats); ws_size >= 58 MB (verified
  // r5/r7 big-path ran).
  hipMemsetAsync((char*)d_ws + 16000000, 0, 16, stream);
  k_mega<<<NBLK, 256, 0, stream>>>(x, y, W1, b1, W2, b2, W3, b3, out, ws);
}

// Round 10
// 1063.107 us; speedup vs baseline: 1.2928x; 1.2928x over previous
//
#include <hip/hip_runtime.h>
#include <math.h>

#define B    32
#define INF  784
#define H1   1024
#define H2   1024
#define NC   10
#define EPSV 0.1f
#define NBLK 768

typedef __attribute__((ext_vector_type(8))) short short8;
typedef __attribute__((ext_vector_type(4))) float floatx4;

__device__ inline ushort bf16_rne(float f) {
  uint u = __builtin_bit_cast(uint, f);
  u += 0x7FFFu + ((u >> 16) & 1u);
  return (ushort)(u >> 16);
}
__device__ inline uint pack2(float a, float b) {
  return (uint)bf16_rne(a) | ((uint)bf16_rne(b) << 16);
}
__device__ inline uint scale_pack(uint u, float d0, float d1v) {
  float f0 = __builtin_bit_cast(float, u << 16) * d0;
  float f1 = __builtin_bit_cast(float, u & 0xFFFF0000u) * d1v;
  uint r0 = __builtin_bit_cast(uint, f0) + 0x8000u;
  uint r1 = __builtin_bit_cast(uint, f1) + 0x8000u;
  return __builtin_amdgcn_perm(r1, r0, 0x07060302u);
}

// ---------------------------------------------------------------------------
// Grid barrier, generation g = 1,2,3,...  (monotonic, no resets).
// 32 arrival counters on separate 256-B lines (24 arrivals each), a 'done'
// line, and a 'gen' line that pollers read (write-once per barrier).
// r9 failed because counter+gen shared one line: 767 pollers fought every
// arrival RMW for the line -> ~170 us/barrier.  This layout decouples them.
// ---------------------------------------------------------------------------
__device__ inline void grid_sync(uint* base, uint g) {
  __syncthreads();
  if (threadIdx.x == 0) {
    __threadfence();
    uint* ctr  = base + (blockIdx.x & 31) * 64;  // 256-B spaced lines
    uint* done = base + 32 * 64;
    uint* gen  = base + 33 * 64;
    uint v = __hip_atomic_fetch_add(ctr, 1u, __ATOMIC_ACQ_REL, __HIP_MEMORY_SCOPE_AGENT) + 1u;
    if (v == g * 24u) {   // this slice complete for barrier g (768/32 = 24)
      uint d = __hip_atomic_fetch_add(done, 1u, __ATOMIC_ACQ_REL, __HIP_MEMORY_SCOPE_AGENT) + 1u;
      if (d == g * 32u) {
        __hip_atomic_store(gen, g, __ATOMIC_RELEASE, __HIP_MEMORY_SCOPE_AGENT);
      }
    }
    while (__hip_atomic_load(gen, __ATOMIC_ACQUIRE, __HIP_MEMORY_SCOPE_AGENT) < g) {
      __builtin_amdgcn_s_sleep(16);
    }
    __threadfence();
  }
  __syncthreads();
}

#define K3_LOAD(c, A, Bv) do {                                                  \
  _Pragma("unroll")                                                             \
  for (int ni = 0; ni < 2; ni++)                                                \
    Bv[ni] = *reinterpret_cast<const uint4*>(bBase + (size_t)(c) * 32768 + ni * 512); \
  _Pragma("unroll")                                                             \
  for (int mi = 0; mi < 7; mi++)                                                \
    A[mi] = *reinterpret_cast<const uint4*>(aBase + (size_t)(c) * 25088 + mi * 512); \
} while (0)

#define K3F_COMP(c, A, Bv) do {                                                 \
  float4 dv0 = *reinterpret_cast<const float4*>(&sm.Ds[(c) * 32 + quad * 8]);   \
  float4 dv1 = *reinterpret_cast<const float4*>(&sm.Ds[(c) * 32 + quad * 8 + 4]);\
  short8 bfr[2];                                                                \
  _Pragma("unroll")                                                             \
  for (int ni = 0; ni < 2; ni++) {                                              \
    uint4 sb;                                                                   \
    sb.x = scale_pack(Bv[ni].x, dv0.x, dv0.y);                                  \
    sb.y = scale_pack(Bv[ni].y, dv0.z, dv0.w);                                  \
    sb.z = scale_pack(Bv[ni].z, dv1.x, dv1.y);                                  \
    sb.w = scale_pack(Bv[ni].w, dv1.z, dv1.w);                                  \
    bfr[ni] = __builtin_bit_cast(short8, sb);                                   \
  }                                                                             \
  _Pragma("unroll")                                                             \
  for (int mi = 0; mi < 7; mi++) {                                              \
    short8 af = __builtin_bit_cast(short8, A[mi]);                              \
    _Pragma("unroll")                                                           \
    for (int ni = 0; ni < 2; ni++)                                              \
      acc[mi][ni] = __builtin_amdgcn_mfma_f32_16x16x32_bf16(af, bfr[ni], acc[mi][ni], 0, 0, 0); \
  }                                                                             \
} while (0)

__global__ __launch_bounds__(256, 3) void k_mega(
    const float* __restrict__ x, const int* __restrict__ y,
    const float* __restrict__ W1, const float* __restrict__ b1,
    const float* __restrict__ W2, const float* __restrict__ b2,
    const float* __restrict__ W3, const float* __restrict__ b3,
    float* __restrict__ out, float* __restrict__ ws)
{
  float* d1B   = ws;
  float* t1B   = ws + 32768;
  float* dnB   = ws + 65536;
  float* E     = ws + 196608;   // 32768, zeroed in P0
  float* F     = ws + 229376;   // 1024, zeroed in P0
  float* F2    = ws + 230400;   // 20480, zeroed in P0
  float* nu2T  = ws + 328704;   // 393216
  ushort* W2F  = (ushort*)(ws + 721920);
  ushort* W1F  = (ushort*)(ws + 1246208);
  float* nu1fT = ws + 328704;   // overlay (after nu2T dead)
  float* hpart = ws + 721920;   // overlay (after W2F/W1F dead)
  float* ppart = ws + 721920;   // overlay (after hpart dead)
  uint* bar    = (uint*)(ws + 4000000);  // 34 lines, zeroed by hipMemsetAsync

  int bid = blockIdx.x;
  int t = threadIdx.x;
  int w = t >> 6, lane = t & 63;
  int quad = lane >> 4, l15 = lane & 15;

  __shared__ union {
    struct { float red[4][B + 1]; float Ts[4][32][17]; } p0;
    float Ds[H1];
    struct { float sA[B], sCl[B], sCu[B], sd2[B], st2[B], sdb[B], swy[B], sw3[NC]; } p2;
    struct { float red[4][2 * NC]; } p4;
    struct { float red[4][NC]; } p6;
  } sm;

  // ================= P0: pack + layer-1 + zero-init (1487 virtual) ========
  for (int vb = bid; vb < 1487; vb += NBLK) {
    __syncthreads();
    if (vb < 64) {
      int jt = vb;
      for (int c = w; c < 32; c += 4) {
        const float* src = &W2[(size_t)(jt * 16 + l15) * H1 + c * 32 + quad * 8];
        float4 v0 = *reinterpret_cast<const float4*>(src);
        float4 v1 = *reinterpret_cast<const float4*>(src + 4);
        uint4 o;
        o.x = pack2(v0.x, v0.y); o.y = pack2(v0.z, v0.w);
        o.z = pack2(v1.x, v1.y); o.w = pack2(v1.z, v1.w);
        *reinterpret_cast<uint4*>(&W2F[((size_t)(c * 64 + jt) * 64 + lane) * 8]) = o;
      }
    } else if (vb < 456) {
      int idx = vb - 64;
      int mt = idx >> 3, cg = idx & 7;
      int c = cg * 4 + w;
      int col0 = mt * 16;
#pragma unroll
      for (int p = 0; p < 8; p++) {
        int r = p * 4 + (lane >> 4);
        sm.p0.Ts[w][r][lane & 15] = W1[(size_t)(c * 32 + r) * INF + col0 + (lane & 15)];
      }
      float f[8];
#pragma unroll
      for (int e = 0; e < 8; e++) f[e] = sm.p0.Ts[w][quad * 8 + e][l15];
      uint4 o;
      o.x = pack2(f[0], f[1]); o.y = pack2(f[2], f[3]);
      o.z = pack2(f[4], f[5]); o.w = pack2(f[6], f[7]);
      *reinterpret_cast<uint4*>(&W1F[((size_t)(c * 49 + mt) * 64 + lane) * 8]) = o;
    } else if (vb < 1480) {
      int i = vb - 456;
      const float* wr = W1 + (size_t)i * INF;
      float acc[B];
#pragma unroll
      for (int b = 0; b < B; b++) acc[b] = 0.f;
      float wabs = 0.f;
      for (int k = t; k < INF; k += 256) {
        float wv = wr[k];
        wabs += fabsf(wv);
#pragma unroll
        for (int b = 0; b < B; b++) acc[b] = fmaf(x[b * INF + k], wv, acc[b]);
      }
#pragma unroll
      for (int off = 32; off > 0; off >>= 1) {
#pragma unroll
        for (int b = 0; b < B; b++) acc[b] += __shfl_down(acc[b], off, 64);
        wabs += __shfl_down(wabs, off, 64);
      }
      if (lane == 0) {
#pragma unroll
        for (int b = 0; b < B; b++) sm.p0.red[w][b] = acc[b];
        sm.p0.red[w][B] = wabs;
      }
      __syncthreads();
      if (t < B) {
        float s = sm.p0.red[0][t] + sm.p0.red[1][t] + sm.p0.red[2][t] + sm.p0.red[3][t];
        float r = EPSV * (sm.p0.red[0][B] + sm.p0.red[1][B] + sm.p0.red[2][B] + sm.p0.red[3][B]);
        float nom = s + b1[i];
        float zl = nom - r, zu = nom + r;
        float d, l;
        if (zl >= 0.f)      { d = 1.f;            l = 0.f; }
        else if (zu > 0.f)  { d = zu / (zu - zl); l = zl;  }
        else                { d = 0.f;            l = 0.f; }
        d1B[(size_t)t * H1 + i] = d;
        t1B[(size_t)t * H1 + i] = d * l;
        dnB[(size_t)t * H1 + i] = d * nom;
      }
    } else {
      int zb = vb - 1480;
      for (int idx = t; idx < 8192; idx += 256) {
        int pos = zb * 8192 + idx;
        if (pos < 54272) E[pos] = 0.f;   // covers E, F, F2 (contiguous)
      }
    }
  }
  grid_sync(bar, 1u);

  // ================= P1: E-GEMM (1792 virtual: x7, y8, b32) ===============
  for (int vb = bid; vb < 1792; vb += NBLK) {
    __syncthreads();
    int xg = vb % 7;
    int rem = vb / 7;
    int yg = rem & 7;
    int b = rem >> 3;
    int mt0 = xg * 7;
    int jt0 = yg * 8 + w * 2;

    for (int idx = t; idx < H1; idx += 256) sm.Ds[idx] = d1B[(size_t)b * H1 + idx];
    __syncthreads();

    const ushort* aBase = W1F + ((size_t)mt0 * 64 + lane) * 8;
    const ushort* bBase = W2F + ((size_t)jt0 * 64 + lane) * 8;

    floatx4 acc[7][2];
#pragma unroll
    for (int mi = 0; mi < 7; mi++)
#pragma unroll
      for (int ni = 0; ni < 2; ni++) acc[mi][ni] = (floatx4){0.f, 0.f, 0.f, 0.f};

    uint4 a0[7], b0[2], a1[7], b1v[2];
    K3_LOAD(0, a0, b0);
    K3_LOAD(1, a1, b1v);
    for (int c = 0; c < 30; c += 2) {
      K3F_COMP(c, a0, b0);
      K3_LOAD(c + 2, a0, b0);
      K3F_COMP(c + 1, a1, b1v);
      if (c + 3 < 32) K3_LOAD(c + 3, a1, b1v);
    }
    K3F_COMP(30, a0, b0);
    K3F_COMP(31, a1, b1v);

#pragma unroll
    for (int ni = 0; ni < 2; ni++) {
      float s = 0.f;
#pragma unroll
      for (int mi = 0; mi < 7; mi++)
#pragma unroll
        for (int r = 0; r < 4; r++) s += fabsf(acc[mi][ni][r]);
      s += __shfl_xor(s, 16, 64);
      s += __shfl_xor(s, 32, 64);
      if (lane < 16) {
        int j = (jt0 + ni) * 16 + l15;
        atomicAdd(&E[(size_t)j * B + b], EPSV * s);
      }
    }
  }
  grid_sync(bar, 2u);

  // ================= P2: k2+k4+k5a fused (1024 virtual, j = vb) ===========
  for (int vb = bid; vb < 1024; vb += NBLK) {
    __syncthreads();
    int j = vb;
    int b0 = w * 8;
    float aA[8] = {}, aCl[8] = {}, aCu[8] = {};
    const float* __restrict__ w2 = W2 + (size_t)j * H1;
    for (int i = lane; i < H1; i += 64) {
      float wv = w2[i];
      float wp = fmaxf(wv, 0.f), wn = fmaxf(-wv, 0.f);
#pragma unroll
      for (int r = 0; r < 8; r++) {
        float dv = dnB[(size_t)(b0 + r) * H1 + i];
        float tv = t1B[(size_t)(b0 + r) * H1 + i];
        aA[r]  = fmaf(wv, dv, aA[r]);
        aCl[r] = fmaf(wn, tv, aCl[r]);
        aCu[r] = fmaf(wp, tv, aCu[r]);
      }
    }
#pragma unroll
    for (int off = 32; off > 0; off >>= 1) {
#pragma unroll
      for (int r = 0; r < 8; r++) {
        aA[r]  += __shfl_down(aA[r],  off, 64);
        aCl[r] += __shfl_down(aCl[r], off, 64);
        aCu[r] += __shfl_down(aCu[r], off, 64);
      }
    }
    float bj = b2[j];
    if (lane == 0) {
#pragma unroll
      for (int r = 0; r < 8; r++) {
        sm.p2.sA [b0 + r] = aA[r] + bj;
        sm.p2.sCl[b0 + r] = aCl[r];
        sm.p2.sCu[b0 + r] = aCu[r];
      }
    }
    if (t >= 64 && t < 96)   sm.p2.swy[t - 64]  = W3[(size_t)y[t - 64] * H2 + j];
    if (t >= 128 && t < 138) sm.p2.sw3[t - 128] = W3[(size_t)(t - 128) * H2 + j];
    __syncthreads();
    if (t < B) {
      float a = sm.p2.sA[t], e = E[(size_t)j * B + t];
      float zl = a - e + sm.p2.sCl[t];
      float zu = a + e - sm.p2.sCu[t];
      float d, l;
      if (zl >= 0.f)      { d = 1.f;            l = 0.f; }
      else if (zu > 0.f)  { d = zu / (zu - zl); l = zl;  }
      else                { d = 0.f;            l = 0.f; }
      sm.p2.sd2[t] = d;
      sm.p2.st2[t] = d * l;
      sm.p2.sdb[t] = d * bj;
    }
    __syncthreads();
    for (int tt = t; tt < B * NC; tt += 256) {   // B*NC=320 > 256: strided
      int b = tt / NC, jc = tt - b * NC;
      float cw = sm.p2.swy[b] - sm.p2.sw3[jc];
      float d2v = sm.p2.sd2[b];
      nu2T[((size_t)b * H2 + j) * 12 + jc] = cw * d2v;
      float val = cw * sm.p2.sdb[b] + fmaxf(-cw, 0.f) * sm.p2.st2[b];
      atomicAdd(&F2[((size_t)(j & 63) * B + b) * NC + jc], val);
    }
  }
  grid_sync(bar, 3u);

  // ================= P3: k5b1 (512 virtual: x2, b32, s8) ==================
  for (int vb = bid; vb < 512; vb += NBLK) {
    int xg = vb & 1, b = (vb >> 1) & 31, s = vb >> 6;
    int i1 = xg * 512 + t * 2;
    const float* __restrict__ nrowb = nu2T + ((size_t)b * H2 + s * 128) * 12;
    const float* __restrict__ w2b = W2 + (size_t)s * 128 * H1 + i1;
    float h0[NC] = {}, h1[NC] = {};
    for (int i2 = 0; i2 < 128; i2++) {
      float2 wv = *reinterpret_cast<const float2*>(&w2b[(size_t)i2 * H1]);
      const float* __restrict__ nrow = nrowb + i2 * 12;
#pragma unroll
      for (int j = 0; j < NC; j++) {
        h0[j] = fmaf(nrow[j], wv.x, h0[j]);
        h1[j] = fmaf(nrow[j], wv.y, h1[j]);
      }
    }
#pragma unroll
    for (int j = 0; j < NC; j++) {
      float2 o; o.x = h0[j]; o.y = h1[j];
      *reinterpret_cast<float2*>(&hpart[(((size_t)s * B + b) * NC + j) * H1 + i1]) = o;
    }
  }
  grid_sync(bar, 4u);

  // ================= P4: k5b2 (128 virtual: x4, b32) ======================
  for (int vb = bid; vb < 128; vb += NBLK) {
    __syncthreads();
    int xg = vb & 3, b = vb >> 2;
    int i1 = xg * 256 + t;
    float d1v = d1B[(size_t)b * H1 + i1];
    float t1v = t1B[(size_t)b * H1 + i1];
    float dnv = dnB[(size_t)b * H1 + i1];
    float sn[NC], c1[NC];
#pragma unroll
    for (int j = 0; j < NC; j++) {
      float hv = 0.f;
#pragma unroll
      for (int s = 0; s < 8; s++)
        hv += hpart[(((size_t)s * B + b) * NC + j) * H1 + i1];
      nu1fT[((size_t)b * H1 + i1) * 12 + j] = hv * d1v;
      sn[j] = hv * dnv;
      c1[j] = fmaxf(-hv, 0.f) * t1v;
    }
#pragma unroll
    for (int off = 32; off > 0; off >>= 1) {
#pragma unroll
      for (int j = 0; j < NC; j++) {
        sn[j] += __shfl_down(sn[j], off, 64);
        c1[j] += __shfl_down(c1[j], off, 64);
      }
    }
    if (lane == 0) {
#pragma unroll
      for (int j = 0; j < NC; j++) { sm.p4.red[w][j] = sn[j]; sm.p4.red[w][NC + j] = c1[j]; }
    }
    __syncthreads();
    if (t < NC) {
      float s = 0.f;
      for (int ww = 0; ww < 4; ww++) s += sm.p4.red[ww][t] + sm.p4.red[ww][NC + t];
      atomicAdd(&F[b * NC + t], s);
    }
  }
  grid_sync(bar, 5u);

  // ================= P5: k5c1 (1024 virtual: kk4, b32, s8; 196 active) ====
  for (int vb = bid; vb < 1024; vb += NBLK) {
    int kk = vb & 3, b = (vb >> 2) & 31, s = vb >> 7;
    bool valid = (t < 196);
    int k = kk * 196 + (valid ? t : 0);
    const float* __restrict__ nrowb = nu1fT + ((size_t)b * H1 + s * 128) * 12;
    const float* __restrict__ w1b = W1 + (size_t)s * 128 * INF + k;
    float acc[NC] = {};
    for (int i1 = 0; i1 < 128; i1++) {
      float w1v = w1b[(size_t)i1 * INF];
      const float* __restrict__ nrow = nrowb + i1 * 12;
#pragma unroll
      for (int j = 0; j < NC; j++) acc[j] = fmaf(nrow[j], w1v, acc[j]);
    }
    if (valid) {
#pragma unroll
      for (int j = 0; j < NC; j++)
        ppart[(((size_t)s * B + b) * NC + j) * INF + k] = acc[j];
    }
  }
  grid_sync(bar, 6u);

  // ================= P6: k5c2 + out (32 virtual) ==========================
  for (int vb = bid; vb < 32; vb += NBLK) {
    __syncthreads();
    int b = vb;
    float e[NC] = {};
    for (int k = t; k < INF; k += 256) {
#pragma unroll
      for (int j = 0; j < NC; j++) {
        float v = 0.f;
#pragma unroll
        for (int s = 0; s < 8; s++)
          v += ppart[(((size_t)s * B + b) * NC + j) * INF + k];
        e[j] += fabsf(v);
      }
    }
#pragma unroll
    for (int off = 32; off > 0; off >>= 1) {
#pragma unroll
      for (int j = 0; j < NC; j++) e[j] += __shfl_down(e[j], off, 64);
    }
    if (lane == 0) {
#pragma unroll
      for (int j = 0; j < NC; j++) sm.p6.red[w][j] = e[j];
    }
    __syncthreads();
    if (t < NC) {
      float ef = 0.f;
      for (int ww = 0; ww < 4; ww++) ef += sm.p6.red[ww][t];
      float s = F[b * NC + t];
      for (int slot = 0; slot < 64; slot++)
        s += F2[((size_t)slot * B + b) * NC + t];
      int yb = y[b];
      s += b3[yb] - b3[t];
      out[b * NC + t] = EPSV * ef - s;
    }
  }
}

// ---------------------------------------------------------------------------
extern "C" void kernel_launch(void* const* d_in, const int* in_sizes, int n_in,
                              void* d_out, int out_size, void* d_ws, size_t ws_size,
                              hipStream_t stream) {
  const float* x  = (const float*)d_in[0];
  const int*   y  = (const int*)  d_in[1];
  const float* W1 = (const float*)d_in[2];
  const float* b1 = (const float*)d_in[3];
  const float* W2 = (const float*)d_in[4];
  const float* b2 = (const float*)d_in[5];
  const float* W3 = (const float*)d_in[6];
  const float* b3 = (const float*)d_in[7];
  float* out = (float*)d_out;
  float* ws  = (float*)d_ws;

  // barrier region: 34 x 256-B lines at byte offset 16,000,000 (beyond all
  // overlays, ws >= 58 MB verified in r5/r7).  Zeroed every launch.
  hipMemsetAsync((char*)d_ws + 16000000, 0, 9216, stream);
  k_mega<<<NBLK, 256, 0, stream>>>(x, y, W1, b1, W2, b2, W3, b3, out, ws);
}

// Round 11
// 481.881 us; speedup vs baseline: 2.8522x; 2.2062x over previous
//
#include <hip/hip_runtime.h>
#include <math.h>

#define B    32
#define INF  784
#define H1   1024
#define H2   1024
#define NC   10
#define EPSV 0.1f
#define NBLK 768

typedef __attribute__((ext_vector_type(8))) short short8;
typedef __attribute__((ext_vector_type(4))) float floatx4;

__device__ inline ushort bf16_rne(float f) {
  uint u = __builtin_bit_cast(uint, f);
  u += 0x7FFFu + ((u >> 16) & 1u);
  return (ushort)(u >> 16);
}
__device__ inline uint pack2(float a, float b) {
  return (uint)bf16_rne(a) | ((uint)bf16_rne(b) << 16);
}
__device__ inline uint scale_pack(uint u, float d0, float d1v) {
  float f0 = __builtin_bit_cast(float, u << 16) * d0;
  float f1 = __builtin_bit_cast(float, u & 0xFFFF0000u) * d1v;
  uint r0 = __builtin_bit_cast(uint, f0) + 0x8000u;
  uint r1 = __builtin_bit_cast(uint, f1) + 0x8000u;
  return __builtin_amdgcn_perm(r1, r0, 0x07060302u);
}

// ---------------------------------------------------------------------------
// Grid barrier, generation g = 1,2,3,... (monotonic).
// ALL atomics RELAXED (coherent-point access, NO per-op cache maintenance).
// r9/r10 lesson: ACQUIRE in the poll loop emits an L2-invalidate per
// iteration -> ~96 pollers/XCD continuously annihilate the L2 of every XCD
// while laggards still compute (~150 us/barrier).  Here the required
// release/acquire fences run exactly once per block per barrier.
// ---------------------------------------------------------------------------
__device__ inline void grid_sync(uint* base, uint g) {
  __syncthreads();
  if (threadIdx.x == 0) {
    __threadfence();   // release: write back this block's phase output (once)
    uint* ctr  = base + (blockIdx.x & 31) * 64;  // 256-B spaced lines
    uint* done = base + 32 * 64;
    uint* gen  = base + 33 * 64;
    uint v = __hip_atomic_fetch_add(ctr, 1u, __ATOMIC_RELAXED, __HIP_MEMORY_SCOPE_AGENT) + 1u;
    if (v == g * 24u) {   // slice complete for barrier g (768/32 = 24)
      uint d = __hip_atomic_fetch_add(done, 1u, __ATOMIC_RELAXED, __HIP_MEMORY_SCOPE_AGENT) + 1u;
      if (d == g * 32u) {
        __hip_atomic_store(gen, g, __ATOMIC_RELAXED, __HIP_MEMORY_SCOPE_AGENT);
      }
    }
    while (__hip_atomic_load(gen, __ATOMIC_RELAXED, __HIP_MEMORY_SCOPE_AGENT) < g) {
      __builtin_amdgcn_s_sleep(32);
    }
    __threadfence();   // acquire: invalidate stale cached producer data (once)
  }
  __syncthreads();
}

#define K3_LOAD(c, A, Bv) do {                                                  \
  _Pragma("unroll")                                                             \
  for (int ni = 0; ni < 2; ni++)                                                \
    Bv[ni] = *reinterpret_cast<const uint4*>(bBase + (size_t)(c) * 32768 + ni * 512); \
  _Pragma("unroll")                                                             \
  for (int mi = 0; mi < 7; mi++)                                                \
    A[mi] = *reinterpret_cast<const uint4*>(aBase + (size_t)(c) * 25088 + mi * 512); \
} while (0)

#define K3F_COMP(c, A, Bv) do {                                                 \
  float4 dv0 = *reinterpret_cast<const float4*>(&sm.Ds[(c) * 32 + quad * 8]);   \
  float4 dv1 = *reinterpret_cast<const float4*>(&sm.Ds[(c) * 32 + quad * 8 + 4]);\
  short8 bfr[2];                                                                \
  _Pragma("unroll")                                                             \
  for (int ni = 0; ni < 2; ni++) {                                              \
    uint4 sb;                                                                   \
    sb.x = scale_pack(Bv[ni].x, dv0.x, dv0.y);                                  \
    sb.y = scale_pack(Bv[ni].y, dv0.z, dv0.w);                                  \
    sb.z = scale_pack(Bv[ni].z, dv1.x, dv1.y);                                  \
    sb.w = scale_pack(Bv[ni].w, dv1.z, dv1.w);                                  \
    bfr[ni] = __builtin_bit_cast(short8, sb);                                   \
  }                                                                             \
  _Pragma("unroll")                                                             \
  for (int mi = 0; mi < 7; mi++) {                                              \
    short8 af = __builtin_bit_cast(short8, A[mi]);                              \
    _Pragma("unroll")                                                           \
    for (int ni = 0; ni < 2; ni++)                                              \
      acc[mi][ni] = __builtin_amdgcn_mfma_f32_16x16x32_bf16(af, bfr[ni], acc[mi][ni], 0, 0, 0); \
  }                                                                             \
} while (0)

__global__ __launch_bounds__(256, 3) void k_mega(
    const float* __restrict__ x, const int* __restrict__ y,
    const float* __restrict__ W1, const float* __restrict__ b1,
    const float* __restrict__ W2, const float* __restrict__ b2,
    const float* __restrict__ W3, const float* __restrict__ b3,
    float* __restrict__ out, float* __restrict__ ws)
{
  float* d1B   = ws;
  float* t1B   = ws + 32768;
  float* dnB   = ws + 65536;
  float* E     = ws + 196608;   // 32768, zeroed in P0
  float* F     = ws + 229376;   // 1024, zeroed in P0
  float* F2    = ws + 230400;   // 20480, zeroed in P0
  float* nu2T  = ws + 328704;   // 393216
  ushort* W2F  = (ushort*)(ws + 721920);
  ushort* W1F  = (ushort*)(ws + 1246208);
  float* nu1fT = ws + 328704;   // overlay (after nu2T dead)
  float* hpart = ws + 721920;   // overlay (after W2F/W1F dead)
  float* ppart = ws + 721920;   // overlay (after hpart dead)
  uint* bar    = (uint*)(ws + 4000000);  // 34 lines, zeroed by hipMemsetAsync

  int bid = blockIdx.x;
  int t = threadIdx.x;
  int w = t >> 6, lane = t & 63;
  int quad = lane >> 4, l15 = lane & 15;

  __shared__ union {
    struct { float red[4][B + 1]; float Ts[4][32][17]; } p0;
    float Ds[H1];
    struct { float sA[B], sCl[B], sCu[B], sd2[B], st2[B], sdb[B], swy[B], sw3[NC]; } p2;
    struct { float red[4][2 * NC]; } p4;
    struct { float red[4][NC]; } p6;
  } sm;

  // ================= P0: pack + layer-1 + zero-init (1487 virtual) ========
  for (int vb = bid; vb < 1487; vb += NBLK) {
    __syncthreads();
    if (vb < 64) {
      int jt = vb;
      for (int c = w; c < 32; c += 4) {
        const float* src = &W2[(size_t)(jt * 16 + l15) * H1 + c * 32 + quad * 8];
        float4 v0 = *reinterpret_cast<const float4*>(src);
        float4 v1 = *reinterpret_cast<const float4*>(src + 4);
        uint4 o;
        o.x = pack2(v0.x, v0.y); o.y = pack2(v0.z, v0.w);
        o.z = pack2(v1.x, v1.y); o.w = pack2(v1.z, v1.w);
        *reinterpret_cast<uint4*>(&W2F[((size_t)(c * 64 + jt) * 64 + lane) * 8]) = o;
      }
    } else if (vb < 456) {
      int idx = vb - 64;
      int mt = idx >> 3, cg = idx & 7;
      int c = cg * 4 + w;
      int col0 = mt * 16;
#pragma unroll
      for (int p = 0; p < 8; p++) {
        int r = p * 4 + (lane >> 4);
        sm.p0.Ts[w][r][lane & 15] = W1[(size_t)(c * 32 + r) * INF + col0 + (lane & 15)];
      }
      float f[8];
#pragma unroll
      for (int e = 0; e < 8; e++) f[e] = sm.p0.Ts[w][quad * 8 + e][l15];
      uint4 o;
      o.x = pack2(f[0], f[1]); o.y = pack2(f[2], f[3]);
      o.z = pack2(f[4], f[5]); o.w = pack2(f[6], f[7]);
      *reinterpret_cast<uint4*>(&W1F[((size_t)(c * 49 + mt) * 64 + lane) * 8]) = o;
    } else if (vb < 1480) {
      int i = vb - 456;
      const float* wr = W1 + (size_t)i * INF;
      float acc[B];
#pragma unroll
      for (int b = 0; b < B; b++) acc[b] = 0.f;
      float wabs = 0.f;
      for (int k = t; k < INF; k += 256) {
        float wv = wr[k];
        wabs += fabsf(wv);
#pragma unroll
        for (int b = 0; b < B; b++) acc[b] = fmaf(x[b * INF + k], wv, acc[b]);
      }
#pragma unroll
      for (int off = 32; off > 0; off >>= 1) {
#pragma unroll
        for (int b = 0; b < B; b++) acc[b] += __shfl_down(acc[b], off, 64);
        wabs += __shfl_down(wabs, off, 64);
      }
      if (lane == 0) {
#pragma unroll
        for (int b = 0; b < B; b++) sm.p0.red[w][b] = acc[b];
        sm.p0.red[w][B] = wabs;
      }
      __syncthreads();
      if (t < B) {
        float s = sm.p0.red[0][t] + sm.p0.red[1][t] + sm.p0.red[2][t] + sm.p0.red[3][t];
        float r = EPSV * (sm.p0.red[0][B] + sm.p0.red[1][B] + sm.p0.red[2][B] + sm.p0.red[3][B]);
        float nom = s + b1[i];
        float zl = nom - r, zu = nom + r;
        float d, l;
        if (zl >= 0.f)      { d = 1.f;            l = 0.f; }
        else if (zu > 0.f)  { d = zu / (zu - zl); l = zl;  }
        else                { d = 0.f;            l = 0.f; }
        d1B[(size_t)t * H1 + i] = d;
        t1B[(size_t)t * H1 + i] = d * l;
        dnB[(size_t)t * H1 + i] = d * nom;
      }
    } else {
      int zb = vb - 1480;
      for (int idx = t; idx < 8192; idx += 256) {
        int pos = zb * 8192 + idx;
        if (pos < 54272) E[pos] = 0.f;   // covers E, F, F2 (contiguous)
      }
    }
  }
  grid_sync(bar, 1u);

  // ================= P1: E-GEMM (1792 virtual: x7, y8, b32) ===============
  for (int vb = bid; vb < 1792; vb += NBLK) {
    __syncthreads();
    int xg = vb % 7;
    int rem = vb / 7;
    int yg = rem & 7;
    int b = rem >> 3;
    int mt0 = xg * 7;
    int jt0 = yg * 8 + w * 2;

    for (int idx = t; idx < H1; idx += 256) sm.Ds[idx] = d1B[(size_t)b * H1 + idx];
    __syncthreads();

    const ushort* aBase = W1F + ((size_t)mt0 * 64 + lane) * 8;
    const ushort* bBase = W2F + ((size_t)jt0 * 64 + lane) * 8;

    floatx4 acc[7][2];
#pragma unroll
    for (int mi = 0; mi < 7; mi++)
#pragma unroll
      for (int ni = 0; ni < 2; ni++) acc[mi][ni] = (floatx4){0.f, 0.f, 0.f, 0.f};

    uint4 a0[7], b0[2], a1[7], b1v[2];
    K3_LOAD(0, a0, b0);
    K3_LOAD(1, a1, b1v);
    for (int c = 0; c < 30; c += 2) {
      K3F_COMP(c, a0, b0);
      K3_LOAD(c + 2, a0, b0);
      K3F_COMP(c + 1, a1, b1v);
      if (c + 3 < 32) K3_LOAD(c + 3, a1, b1v);
    }
    K3F_COMP(30, a0, b0);
    K3F_COMP(31, a1, b1v);

#pragma unroll
    for (int ni = 0; ni < 2; ni++) {
      float s = 0.f;
#pragma unroll
      for (int mi = 0; mi < 7; mi++)
#pragma unroll
        for (int r = 0; r < 4; r++) s += fabsf(acc[mi][ni][r]);
      s += __shfl_xor(s, 16, 64);
      s += __shfl_xor(s, 32, 64);
      if (lane < 16) {
        int j = (jt0 + ni) * 16 + l15;
        atomicAdd(&E[(size_t)j * B + b], EPSV * s);
      }
    }
  }
  grid_sync(bar, 2u);

  // ================= P2: k2+k4+k5a fused (1024 virtual, j = vb) ===========
  for (int vb = bid; vb < 1024; vb += NBLK) {
    __syncthreads();
    int j = vb;
    int b0 = w * 8;
    float aA[8] = {}, aCl[8] = {}, aCu[8] = {};
    const float* __restrict__ w2 = W2 + (size_t)j * H1;
    for (int i = lane; i < H1; i += 64) {
      float wv = w2[i];
      float wp = fmaxf(wv, 0.f), wn = fmaxf(-wv, 0.f);
#pragma unroll
      for (int r = 0; r < 8; r++) {
        float dv = dnB[(size_t)(b0 + r) * H1 + i];
        float tv = t1B[(size_t)(b0 + r) * H1 + i];
        aA[r]  = fmaf(wv, dv, aA[r]);
        aCl[r] = fmaf(wn, tv, aCl[r]);
        aCu[r] = fmaf(wp, tv, aCu[r]);
      }
    }
#pragma unroll
    for (int off = 32; off > 0; off >>= 1) {
#pragma unroll
      for (int r = 0; r < 8; r++) {
        aA[r]  += __shfl_down(aA[r],  off, 64);
        aCl[r] += __shfl_down(aCl[r], off, 64);
        aCu[r] += __shfl_down(aCu[r], off, 64);
      }
    }
    float bj = b2[j];
    if (lane == 0) {
#pragma unroll
      for (int r = 0; r < 8; r++) {
        sm.p2.sA [b0 + r] = aA[r] + bj;
        sm.p2.sCl[b0 + r] = aCl[r];
        sm.p2.sCu[b0 + r] = aCu[r];
      }
    }
    if (t >= 64 && t < 96)   sm.p2.swy[t - 64]  = W3[(size_t)y[t - 64] * H2 + j];
    if (t >= 128 && t < 138) sm.p2.sw3[t - 128] = W3[(size_t)(t - 128) * H2 + j];
    __syncthreads();
    if (t < B) {
      float a = sm.p2.sA[t], e = E[(size_t)j * B + t];
      float zl = a - e + sm.p2.sCl[t];
      float zu = a + e - sm.p2.sCu[t];
      float d, l;
      if (zl >= 0.f)      { d = 1.f;            l = 0.f; }
      else if (zu > 0.f)  { d = zu / (zu - zl); l = zl;  }
      else                { d = 0.f;            l = 0.f; }
      sm.p2.sd2[t] = d;
      sm.p2.st2[t] = d * l;
      sm.p2.sdb[t] = d * bj;
    }
    __syncthreads();
    for (int tt = t; tt < B * NC; tt += 256) {   // B*NC=320 > 256: strided
      int b = tt / NC, jc = tt - b * NC;
      float cw = sm.p2.swy[b] - sm.p2.sw3[jc];
      float d2v = sm.p2.sd2[b];
      nu2T[((size_t)b * H2 + j) * 12 + jc] = cw * d2v;
      float val = cw * sm.p2.sdb[b] + fmaxf(-cw, 0.f) * sm.p2.st2[b];
      atomicAdd(&F2[((size_t)(j & 63) * B + b) * NC + jc], val);
    }
  }
  grid_sync(bar, 3u);

  // ================= P3: k5b1 (512 virtual: x2, b32, s8) ==================
  for (int vb = bid; vb < 512; vb += NBLK) {
    int xg = vb & 1, b = (vb >> 1) & 31, s = vb >> 6;
    int i1 = xg * 512 + t * 2;
    const float* __restrict__ nrowb = nu2T + ((size_t)b * H2 + s * 128) * 12;
    const float* __restrict__ w2b = W2 + (size_t)s * 128 * H1 + i1;
    float h0[NC] = {}, h1[NC] = {};
    for (int i2 = 0; i2 < 128; i2++) {
      float2 wv = *reinterpret_cast<const float2*>(&w2b[(size_t)i2 * H1]);
      const float* __restrict__ nrow = nrowb + i2 * 12;
#pragma unroll
      for (int j = 0; j < NC; j++) {
        h0[j] = fmaf(nrow[j], wv.x, h0[j]);
        h1[j] = fmaf(nrow[j], wv.y, h1[j]);
      }
    }
#pragma unroll
    for (int j = 0; j < NC; j++) {
      float2 o; o.x = h0[j]; o.y = h1[j];
      *reinterpret_cast<float2*>(&hpart[(((size_t)s * B + b) * NC + j) * H1 + i1]) = o;
    }
  }
  grid_sync(bar, 4u);

  // ================= P4: k5b2 (128 virtual: x4, b32) ======================
  for (int vb = bid; vb < 128; vb += NBLK) {
    __syncthreads();
    int xg = vb & 3, b = vb >> 2;
    int i1 = xg * 256 + t;
    float d1v = d1B[(size_t)b * H1 + i1];
    float t1v = t1B[(size_t)b * H1 + i1];
    float dnv = dnB[(size_t)b * H1 + i1];
    float sn[NC], c1[NC];
#pragma unroll
    for (int j = 0; j < NC; j++) {
      float hv = 0.f;
#pragma unroll
      for (int s = 0; s < 8; s++)
        hv += hpart[(((size_t)s * B + b) * NC + j) * H1 + i1];
      nu1fT[((size_t)b * H1 + i1) * 12 + j] = hv * d1v;
      sn[j] = hv * dnv;
      c1[j] = fmaxf(-hv, 0.f) * t1v;
    }
#pragma unroll
    for (int off = 32; off > 0; off >>= 1) {
#pragma unroll
      for (int j = 0; j < NC; j++) {
        sn[j] += __shfl_down(sn[j], off, 64);
        c1[j] += __shfl_down(c1[j], off, 64);
      }
    }
    if (lane == 0) {
#pragma unroll
      for (int j = 0; j < NC; j++) { sm.p4.red[w][j] = sn[j]; sm.p4.red[w][NC + j] = c1[j]; }
    }
    __syncthreads();
    if (t < NC) {
      float s = 0.f;
      for (int ww = 0; ww < 4; ww++) s += sm.p4.red[ww][t] + sm.p4.red[ww][NC + t];
      atomicAdd(&F[b * NC + t], s);
    }
  }
  grid_sync(bar, 5u);

  // ================= P5: k5c1 (1024 virtual: kk4, b32, s8; 196 active) ====
  for (int vb = bid; vb < 1024; vb += NBLK) {
    int kk = vb & 3, b = (vb >> 2) & 31, s = vb >> 7;
    bool valid = (t < 196);
    int k = kk * 196 + (valid ? t : 0);
    const float* __restrict__ nrowb = nu1fT + ((size_t)b * H1 + s * 128) * 12;
    const float* __restrict__ w1b = W1 + (size_t)s * 128 * INF + k;
    float acc[NC] = {};
    for (int i1 = 0; i1 < 128; i1++) {
      float w1v = w1b[(size_t)i1 * INF];
      const float* __restrict__ nrow = nrowb + i1 * 12;
#pragma unroll
      for (int j = 0; j < NC; j++) acc[j] = fmaf(nrow[j], w1v, acc[j]);
    }
    if (valid) {
#pragma unroll
      for (int j = 0; j < NC; j++)
        ppart[(((size_t)s * B + b) * NC + j) * INF + k] = acc[j];
    }
  }
  grid_sync(bar, 6u);

  // ================= P6: k5c2 + out (32 virtual) ==========================
  for (int vb = bid; vb < 32; vb += NBLK) {
    __syncthreads();
    int b = vb;
    float e[NC] = {};
    for (int k = t; k < INF; k += 256) {
#pragma unroll
      for (int j = 0; j < NC; j++) {
        float v = 0.f;
#pragma unroll
        for (int s = 0; s < 8; s++)
          v += ppart[(((size_t)s * B + b) * NC + j) * INF + k];
        e[j] += fabsf(v);
      }
    }
#pragma unroll
    for (int off = 32; off > 0; off >>= 1) {
#pragma unroll
      for (int j = 0; j < NC; j++) e[j] += __shfl_down(e[j], off, 64);
    }
    if (lane == 0) {
#pragma unroll
      for (int j = 0; j < NC; j++) sm.p6.red[w][j] = e[j];
    }
    __syncthreads();
    if (t < NC) {
      float ef = 0.f;
      for (int ww = 0; ww < 4; ww++) ef += sm.p6.red[ww][t];
      float s = F[b * NC + t];
      for (int slot = 0; slot < 64; slot++)
        s += F2[((size_t)slot * B + b) * NC + t];
      int yb = y[b];
      s += b3[yb] - b3[t];
      out[b * NC + t] = EPSV * ef - s;
    }
  }
}

// ---------------------------------------------------------------------------
extern "C" void kernel_launch(void* const* d_in, const int* in_sizes, int n_in,
                              void* d_out, int out_size, void* d_ws, size_t ws_size,
                              hipStream_t stream) {
  const float* x  = (const float*)d_in[0];
  const int*   y  = (const int*)  d_in[1];
  const float* W1 = (const float*)d_in[2];
  const float* b1 = (const float*)d_in[3];
  const float* W2 = (const float*)d_in[4];
  const float* b2 = (const float*)d_in[5];
  const float* W3 = (const float*)d_in[6];
  const float* b3 = (const float*)d_in[7];
  float* out = (float*)d_out;
  float* ws  = (float*)d_ws;

  // barrier region: 34 x 256-B lines at byte offset 16,000,000 (beyond all
  // overlays, ws >= 58 MB verified in r5/r7).  Zeroed every launch.
  hipMemsetAsync((char*)d_ws + 16000000, 0, 9216, stream);
  k_mega<<<NBLK, 256, 0, stream>>>(x, y, W1, b1, W2, b2, W3, b3, out, ws);
}